// Round 15
// baseline (459.644 us; speedup 1.0000x reference)
//
#include <hip/hip_runtime.h>
#include <hip/hip_bf16.h>

typedef __attribute__((ext_vector_type(8))) __bf16 bf16x8;
typedef __attribute__((ext_vector_type(4))) __bf16 bf16x4;
typedef __attribute__((ext_vector_type(4))) float f32x4;

#define MFMA16(a, b, c) __builtin_amdgcn_mfma_f32_16x16x32_bf16((a), (b), (c), 0, 0, 0)

#if __has_builtin(__builtin_amdgcn_exp2f)
#define EXP2F(x) __builtin_amdgcn_exp2f(x)
#else
#define EXP2F(x) exp2f(x)
#endif

#define GLDS16(g, l)                                                             \
    __builtin_amdgcn_global_load_lds((const __attribute__((address_space(1))) void*)(g), \
                                     (__attribute__((address_space(3))) void*)(l), 16, 0, 0)

#define BARRIER()                          \
    do {                                   \
        asm volatile("" ::: "memory");     \
        __builtin_amdgcn_s_barrier();      \
        asm volatile("" ::: "memory");     \
    } while (0)

#define VM8 asm volatile("s_waitcnt vmcnt(8)" ::: "memory")
#define VM0 asm volatile("s_waitcnt vmcnt(0)" ::: "memory")

static __device__ __forceinline__ unsigned short cvt_bf(float f) {
    return __builtin_bit_cast(unsigned short, (__bf16)f);
}

static __device__ __forceinline__ bf16x8 bf8_zero() {
    uint4 z = make_uint4(0, 0, 0, 0);
    return __builtin_bit_cast(bf16x8, z);
}

// ---------------- prep: x fp32->bf16 + all 4 weight transposes, ONE launch ----------
__global__ __launch_bounds__(256) void prep(const float* __restrict__ X,
                                            const float* __restrict__ Wq,
                                            const float* __restrict__ Wc,
                                            const float* __restrict__ Wk,
                                            const float* __restrict__ Wv,
                                            unsigned short* __restrict__ Xb,
                                            unsigned short* __restrict__ dqc,
                                            unsigned short* __restrict__ dkv) {
    const int D = 5120, L = 1536;
    int b = blockIdx.x, t = threadIdx.x;
    if (b < 5120) {
        int i = (b * 256 + t) * 8;
        float4 f0 = *(const float4*)(X + i);
        float4 f1 = *(const float4*)(X + i + 4);
        unsigned short o[8];
        o[0] = cvt_bf(f0.x); o[1] = cvt_bf(f0.y); o[2] = cvt_bf(f0.z); o[3] = cvt_bf(f0.w);
        o[4] = cvt_bf(f1.x); o[5] = cvt_bf(f1.y); o[6] = cvt_bf(f1.z); o[7] = cvt_bf(f1.w);
        *(uint4*)(Xb + i) = *(const uint4*)o;
        return;
    }
    int b2 = b - 5120;
    const float* W;
    unsigned short* WT;
    int K, N;
    if (b2 < 6400) { W = Wq; WT = dqc; K = D; N = D; }
    else if (b2 < 8320) { b2 -= 6400; W = Wc; WT = dqc + (size_t)D * D; K = D; N = L; }
    else if (b2 < 10240) { b2 -= 8320; W = Wk; WT = dkv; K = L; N = D; }
    else { b2 -= 10240; W = Wv; WT = dkv + (size_t)D * L; K = L; N = D; }
    int nx = N / 64;
    int n0 = (b2 % nx) * 64, k0 = (b2 / nx) * 64;

    __shared__ unsigned short tile[64][65];
    int c4 = (t & 15) * 4, r16 = t >> 4;
#pragma unroll
    for (int it = 0; it < 4; ++it) {
        int r = r16 + it * 16;
        float4 f = *(const float4*)&W[(size_t)(k0 + r) * N + n0 + c4];
        tile[r][c4 + 0] = cvt_bf(f.x);
        tile[r][c4 + 1] = cvt_bf(f.y);
        tile[r][c4 + 2] = cvt_bf(f.z);
        tile[r][c4 + 3] = cvt_bf(f.w);
    }
    __syncthreads();
    int n = t >> 2, kc = (t & 3) * 16;
    unsigned short o[16];
#pragma unroll
    for (int j = 0; j < 16; ++j) o[j] = tile[kc + j][n];
    unsigned short* dst = &WT[(size_t)(n0 + n) * K + k0 + kc];
    *(uint4*)dst = *(const uint4*)o;
    *(uint4*)(dst + 8) = *(const uint4*)(o + 8);
}

// ================= 128x128 2-blocks/CU bf16 GEMM (now used for BOTH GEMMs) =========
// Proven R5 pipeline: gload_lds staging both operands, dbuf, counted vmcnt(8),
// slot^(row&7) XOR swizzle, setprio around MFMA cluster. Epilogue generalized:
//   col <  nsplit: C[row][col] = (acc+bias0[col]) * s0
//   col >= nsplit: VT ? VT[col-nsplit][row] = acc+bias1 (transposed v-path)
//                     : C[row][col] = (acc+bias1[col-nsplit]) * s1
// Bijective XCD remap (requires grid%8==0; 832 and 1280 both qualify).
#define STG128(S, KT)                                                                  \
    do {                                                                               \
        _Pragma("unroll") for (int i_ = 0; i_ < 4; ++i_)                               \
            GLDS16(Ag + (size_t)(i_ * 32) * lda + (size_t)(KT) * 64,                   \
                   &Abuf[S][i_ * 2048 + wid * 512]);                                   \
        _Pragma("unroll") for (int i_ = 0; i_ < 4; ++i_)                               \
            GLDS16(Bg + (size_t)(i_ * 32) * ldb + (size_t)(KT) * 64,                   \
                   &Bbuf[S][i_ * 2048 + wid * 512]);                                   \
    } while (0)

__global__ __launch_bounds__(256, 2) void gemm128(const unsigned short* __restrict__ A, int lda,
                                                  const unsigned short* __restrict__ BT, int ldb,
                                                  const float* __restrict__ bias0,
                                                  const float* __restrict__ bias1, int nsplit,
                                                  unsigned short* __restrict__ C, int ldc,
                                                  unsigned short* __restrict__ VT,
                                                  int K, float s0, float s1, int gy) {
    __shared__ __align__(16) unsigned short Abuf[2][8192];  // 2 x 16KB
    __shared__ __align__(16) unsigned short Bbuf[2][8192];

    int b = blockIdx.x;
    int wgid = (b & 7) * (gridDim.x >> 3) + (b >> 3);  // bijective XCD remap
    int tm = wgid % gy, tn = wgid / gy;                // tm-inner within each tn column
    int m0 = tm * 128, n0 = tn * 128;
    int tid = threadIdx.x, lane = tid & 63, wid = tid >> 6;
    int wm = wid >> 1, wn = wid & 1;
    int lrow = lane & 15, lkg = lane >> 4;

    int srow = tid >> 3;
    int cole = ((tid & 7) ^ ((tid >> 3) & 7)) << 3;
    const unsigned short* Ag = A + (size_t)(m0 + srow) * lda + cole;
    const unsigned short* Bg = BT + (size_t)(n0 + srow) * ldb + cole;

    int xorc8 = (lrow & 7) << 3;
    int aoff = (wm * 64 + lrow) * 64;
    int boff = (wn * 64 + lrow) * 64;

    f32x4 acc[4][4];
#pragma unroll
    for (int i2 = 0; i2 < 4; ++i2)
#pragma unroll
        for (int j = 0; j < 4; ++j) acc[i2][j] = (f32x4){0.f, 0.f, 0.f, 0.f};

    const int nkt = K >> 6;
    STG128(0, 0);
    for (int t = 0; t < nkt; ++t) {
        const int cur = t & 1;
        if (t + 1 < nkt) {
            STG128(cur ^ 1, t + 1);
            VM8;
        } else {
            VM0;
        }
        BARRIER();
        bf16x8 af[4][2], bv[4][2];
#pragma unroll
        for (int mi = 0; mi < 4; ++mi)
#pragma unroll
            for (int kh = 0; kh < 2; ++kh)
                af[mi][kh] = *(const bf16x8*)&Abuf[cur][aoff + mi * 1024 + (((kh * 4 + lkg) << 3) ^ xorc8)];
#pragma unroll
        for (int ni = 0; ni < 4; ++ni)
#pragma unroll
            for (int kh = 0; kh < 2; ++kh)
                bv[ni][kh] = *(const bf16x8*)&Bbuf[cur][boff + ni * 1024 + (((kh * 4 + lkg) << 3) ^ xorc8)];
        __builtin_amdgcn_s_setprio(1);
#pragma unroll
        for (int mi = 0; mi < 4; ++mi)
#pragma unroll
            for (int ni = 0; ni < 4; ++ni)
#pragma unroll
                for (int kh = 0; kh < 2; ++kh)
                    acc[mi][ni] = MFMA16(af[mi][kh], bv[ni][kh], acc[mi][ni]);
        __builtin_amdgcn_s_setprio(0);
        BARRIER();
    }

#pragma unroll
    for (int ni = 0; ni < 4; ++ni) {
        int col = n0 + wn * 64 + ni * 16 + lrow;
        float bval = (col < nsplit) ? bias0[col] : bias1[col - nsplit];
        float scl = (col < nsplit) ? s0 : s1;
#pragma unroll
        for (int mi = 0; mi < 4; ++mi) {
            int row = m0 + wm * 64 + mi * 16 + lkg * 4;
            if (VT == nullptr || col < nsplit) {
#pragma unroll
                for (int j = 0; j < 4; ++j)
                    C[(size_t)(row + j) * ldc + col] = cvt_bf((acc[mi][ni][j] + bval) * scl);
            } else {
                ushort4 o;
                o.x = cvt_bf(acc[mi][ni][0] + bval);
                o.y = cvt_bf(acc[mi][ni][1] + bval);
                o.z = cvt_bf(acc[mi][ni][2] + bval);
                o.w = cvt_bf(acc[mi][ni][3] + bval);
                *(ushort4*)&VT[(size_t)(col - nsplit) * 2048 + row] = o;
            }
        }
    }
}

// ---------------- flash attention: 256 q-rows/block (8 waves x 2 row-groups) ---------
__global__ __launch_bounds__(512) void attn(const unsigned short* __restrict__ q, int ldq,
                                            const unsigned short* __restrict__ k, int ldk,
                                            const unsigned short* __restrict__ vT,
                                            float* __restrict__ out) {
    const int S = 1024, D = 5120, Dh = 40;
    int b = blockIdx.z, h = blockIdx.y, qt = blockIdx.x;
    int t = threadIdx.x, lane = t & 63, wid = t >> 6;
    int lrow = lane & 15, lkg = lane >> 4;

    __shared__ __align__(16) unsigned short Ks[64 * 72];
    __shared__ __align__(16) unsigned short Vs[48 * 72];     // [d][key], rows 40..47 zero
    __shared__ __align__(16) unsigned short Ps[8][16 * 72];

    const size_t qbase = ((size_t)b * S) * ldq + (size_t)h * Dh;
    int q0 = qt * 256 + wid * 32;

    for (int z = t; z < 8 * 72; z += 512) Vs[40 * 72 + z] = 0;

    bf16x8 qf[2][2];
#pragma unroll
    for (int g = 0; g < 2; ++g) {
        const unsigned short* qp = q + qbase + (size_t)(q0 + g * 16 + lrow) * ldq;
        qf[g][0] = *(const bf16x8*)(qp + lkg * 8);
        qf[g][1] = (lkg == 0) ? *(const bf16x8*)(qp + 32) : bf8_zero();
    }

    int rrK = t >> 3, ccK = t & 7;
    int dV = t >> 3, cV = t & 7;
    int dVc = (dV < 40) ? dV : 39;
    const unsigned short* kp = k + ((size_t)b * S) * ldk + (size_t)h * Dh +
                               (size_t)rrK * ldk + ccK * 8;
    const unsigned short* vp = vT + (size_t)(h * Dh + dVc) * 2048 + b * S + cV * 8;
    const size_t kstep = (size_t)64 * ldk;

    uint4 kv0 = make_uint4(0, 0, 0, 0), va0 = make_uint4(0, 0, 0, 0);
    if (ccK < 5) kv0 = *(const uint4*)kp;
    if (dV < 40) va0 = *(const uint4*)vp;
    kp += kstep; vp += 64;

    f32x4 acc[2][3];
#pragma unroll
    for (int g = 0; g < 2; ++g)
#pragma unroll
        for (int nb = 0; nb < 3; ++nb) acc[g][nb] = (f32x4){0.f, 0.f, 0.f, 0.f};
    float mrun[2] = {-INFINITY, -INFINITY}, lrun[2] = {0.f, 0.f};

    for (int kt = 0; kt < 16; ++kt) {
        __syncthreads();
        uint4 w0 = (ccK < 5) ? kv0 : make_uint4(0, 0, 0, 0);
        *(uint4*)&Ks[rrK * 72 + ccK * 8] = w0;
        if (dV < 40) *(uint4*)&Vs[dV * 72 + cV * 8] = va0;
        __syncthreads();
        if (kt + 1 < 16) {
            if (ccK < 5) kv0 = *(const uint4*)kp;
            if (dV < 40) va0 = *(const uint4*)vp;
            kp += kstep; vp += 64;
        }

#pragma unroll
        for (int g = 0; g < 2; ++g) {
            f32x4 sf[4];
            __builtin_amdgcn_s_setprio(1);
#pragma unroll
            for (int nb = 0; nb < 4; ++nb) {
                sf[nb] = (f32x4){0.f, 0.f, 0.f, 0.f};
                bf16x8 kf0 = *(const bf16x8*)&Ks[(nb * 16 + lrow) * 72 + lkg * 8];
                bf16x8 kf1 = *(const bf16x8*)&Ks[(nb * 16 + lrow) * 72 + 32 + lkg * 8];
                sf[nb] = MFMA16(kf0, qf[g][0], sf[nb]);
                sf[nb] = MFMA16(kf1, qf[g][1], sf[nb]);
            }
            __builtin_amdgcn_s_setprio(0);

            float tm = sf[0][0];
#pragma unroll
            for (int nb = 0; nb < 4; ++nb)
#pragma unroll
                for (int i = 0; i < 4; ++i) tm = fmaxf(tm, sf[nb][i]);
            tm = fmaxf(tm, __shfl_xor(tm, 16));
            tm = fmaxf(tm, __shfl_xor(tm, 32));

            float mn = mrun[g], al = 1.0f;
            bool resc = !__all(tm <= mrun[g] + 11.0f);
            if (resc) {
                mn = fmaxf(mrun[g], tm);
                al = EXP2F(mrun[g] - mn);
                mrun[g] = mn;
            }
            float rs = 0.f;
#pragma unroll
            for (int nb = 0; nb < 4; ++nb) {
                bf16x4 pk;
#pragma unroll
                for (int i = 0; i < 4; ++i) {
                    float p = EXP2F(sf[nb][i] - mn);
                    rs += p;
                    pk[i] = (__bf16)p;
                }
                *(bf16x4*)&Ps[wid][lrow * 72 + nb * 16 + lkg * 4] = pk;
            }
            rs += __shfl_xor(rs, 16);
            rs += __shfl_xor(rs, 32);
            lrun[g] = lrun[g] * al + rs;

            if (resc) {
                float alr[4];
#pragma unroll
                for (int i = 0; i < 4; ++i) alr[i] = __shfl(al, lkg * 4 + i);
#pragma unroll
                for (int nb = 0; nb < 3; ++nb)
#pragma unroll
                    for (int i = 0; i < 4; ++i) acc[g][nb][i] *= alr[i];
            }

            __builtin_amdgcn_s_setprio(1);
#pragma unroll
            for (int kk = 0; kk < 2; ++kk) {
                bf16x8 pf = *(const bf16x8*)&Ps[wid][lrow * 72 + kk * 32 + lkg * 8];
#pragma unroll
                for (int nb = 0; nb < 3; ++nb) {
                    bf16x8 vf = *(const bf16x8*)&Vs[(nb * 16 + lrow) * 72 + kk * 32 + lkg * 8];
                    acc[g][nb] = MFMA16(pf, vf, acc[g][nb]);
                }
            }
            __builtin_amdgcn_s_setprio(0);
        }
    }

#pragma unroll
    for (int g = 0; g < 2; ++g) {
        float lr[4];
#pragma unroll
        for (int i = 0; i < 4; ++i) lr[i] = __shfl(lrun[g], lkg * 4 + i);
#pragma unroll
        for (int i = 0; i < 4; ++i) {
            float inv = 1.0f / lr[i];
            int s = q0 + g * 16 + lkg * 4 + i;
#pragma unroll
            for (int nb = 0; nb < 3; ++nb) {
                int d = nb * 16 + lrow;
                if (d < Dh) out[((size_t)(b * S + s)) * D + h * Dh + d] = acc[g][nb][i] * inv;
            }
        }
    }
}

extern "C" void kernel_launch(void* const* d_in, const int* in_sizes, int n_in,
                              void* d_out, int out_size, void* d_ws, size_t ws_size,
                              hipStream_t stream) {
    const int M = 2048, D = 5120, L = 1536, NQ = D + L /*6656*/, NKV = 2 * D /*10240*/;
    const float* x  = (const float*)d_in[0];
    const float* Wq = (const float*)d_in[1];
    const float* bq = (const float*)d_in[2];
    const float* Wc = (const float*)d_in[3];
    const float* bc = (const float*)d_in[4];
    const float* Wk = (const float*)d_in[5];
    const float* bk = (const float*)d_in[6];
    const float* Wv = (const float*)d_in[7];
    const float* bv = (const float*)d_in[8];
    float* out = (float*)d_out;

    unsigned short* ws = (unsigned short*)d_ws;
    size_t off = 0;
    unsigned short* xb    = ws + off; off += (size_t)M * D;
    unsigned short* WqcT  = ws + off; off += (size_t)NQ * D;   // [Wq|Wc]^T
    unsigned short* WkvT  = ws + off; off += (size_t)NKV * L;  // [Wk|Wv]^T
    unsigned short* qkvb  = ws + off; off += (size_t)M * NQ;   // [q | kv_latent]
    unsigned short* kvout = ws + off; off += (size_t)M * NKV;  // [k | (v unused)]
    unsigned short* vTb   = ws + off; off += (size_t)D * M;    // v^T [5120][2048]

    prep<<<17280, 256, 0, stream>>>(x, Wq, Wc, Wk, Wv, xb, WqcT, WkvT);

    const float qscale = 1.4426950408889634f / 6.324555320336759f;  // log2(e)/sqrt(40)

    // GEMM1: [q | kv_latent] = x @ [Wq | Wc]   grid 832 (52x16), 128^2 2-blk/CU
    gemm128<<<dim3((NQ / 128) * (M / 128)), 256, 0, stream>>>(xb, D, WqcT, D, bq, bc, D,
                                                              qkvb, NQ, (unsigned short*)nullptr,
                                                              D, qscale, 1.0f, M / 128);
    // GEMM2: [k | v] = kv_latent @ [Wk | Wv]; k -> kvout, v -> vTb (transposed epilogue)
    gemm128<<<dim3((NKV / 128) * (M / 128)), 256, 0, stream>>>(qkvb + D, NQ, WkvT, L, bk, bv, D,
                                                               kvout, NKV, vTb, L, 1.0f, 1.0f,
                                                               M / 128);

    attn<<<dim3(1024 / 256, 128, 2), 512, 0, stream>>>(qkvb, NQ, kvout, NKV, vTb, out);
}

// Round 16
// 436.500 us; speedup vs baseline: 1.0530x; 1.0530x over previous
//
#include <hip/hip_runtime.h>
#include <hip/hip_bf16.h>

typedef __attribute__((ext_vector_type(8))) __bf16 bf16x8;
typedef __attribute__((ext_vector_type(4))) __bf16 bf16x4;
typedef __attribute__((ext_vector_type(4))) float f32x4;

#define MFMA16(a, b, c) __builtin_amdgcn_mfma_f32_16x16x32_bf16((a), (b), (c), 0, 0, 0)

#if __has_builtin(__builtin_amdgcn_exp2f)
#define EXP2F(x) __builtin_amdgcn_exp2f(x)
#else
#define EXP2F(x) exp2f(x)
#endif

#define GLDS16(g, l)                                                             \
    __builtin_amdgcn_global_load_lds((const __attribute__((address_space(1))) void*)(g), \
                                     (__attribute__((address_space(3))) void*)(l), 16, 0, 0)

#define BARRIER()                          \
    do {                                   \
        asm volatile("" ::: "memory");     \
        __builtin_amdgcn_s_barrier();      \
        asm volatile("" ::: "memory");     \
    } while (0)

#define WAIT_LGKM0() asm volatile("s_waitcnt lgkmcnt(0)" ::: "memory")
#define VM6 asm volatile("s_waitcnt vmcnt(6)" ::: "memory")
#define VM8 asm volatile("s_waitcnt vmcnt(8)" ::: "memory")
#define VM0 asm volatile("s_waitcnt vmcnt(0)" ::: "memory")
#define VMNONE ((void)0)
#define KEEP(x) x
#define DROP(x)

static __device__ __forceinline__ unsigned short cvt_bf(float f) {
    return __builtin_bit_cast(unsigned short, (__bf16)f);
}

static __device__ __forceinline__ bf16x8 bf8_zero() {
    uint4 z = make_uint4(0, 0, 0, 0);
    return __builtin_bit_cast(bf16x8, z);
}

// ---------------- prep: x fp32->bf16 + all 4 weight transposes, ONE launch ----------
__global__ __launch_bounds__(256) void prep(const float* __restrict__ X,
                                            const float* __restrict__ Wq,
                                            const float* __restrict__ Wc,
                                            const float* __restrict__ Wk,
                                            const float* __restrict__ Wv,
                                            unsigned short* __restrict__ Xb,
                                            unsigned short* __restrict__ dqc,
                                            unsigned short* __restrict__ dkv) {
    const int D = 5120, L = 1536;
    int b = blockIdx.x, t = threadIdx.x;
    if (b < 5120) {
        int i = (b * 256 + t) * 8;
        float4 f0 = *(const float4*)(X + i);
        float4 f1 = *(const float4*)(X + i + 4);
        unsigned short o[8];
        o[0] = cvt_bf(f0.x); o[1] = cvt_bf(f0.y); o[2] = cvt_bf(f0.z); o[3] = cvt_bf(f0.w);
        o[4] = cvt_bf(f1.x); o[5] = cvt_bf(f1.y); o[6] = cvt_bf(f1.z); o[7] = cvt_bf(f1.w);
        *(uint4*)(Xb + i) = *(const uint4*)o;
        return;
    }
    int b2 = b - 5120;
    const float* W;
    unsigned short* WT;
    int K, N;
    if (b2 < 6400) { W = Wq; WT = dqc; K = D; N = D; }
    else if (b2 < 8320) { b2 -= 6400; W = Wc; WT = dqc + (size_t)D * D; K = D; N = L; }
    else if (b2 < 10240) { b2 -= 8320; W = Wk; WT = dkv; K = L; N = D; }
    else { b2 -= 10240; W = Wv; WT = dkv + (size_t)D * L; K = L; N = D; }
    int nx = N / 64;
    int n0 = (b2 % nx) * 64, k0 = (b2 / nx) * 64;

    __shared__ unsigned short tile[64][65];
    int c4 = (t & 15) * 4, r16 = t >> 4;
#pragma unroll
    for (int it = 0; it < 4; ++it) {
        int r = r16 + it * 16;
        float4 f = *(const float4*)&W[(size_t)(k0 + r) * N + n0 + c4];
        tile[r][c4 + 0] = cvt_bf(f.x);
        tile[r][c4 + 1] = cvt_bf(f.y);
        tile[r][c4 + 2] = cvt_bf(f.z);
        tile[r][c4 + 3] = cvt_bf(f.w);
    }
    __syncthreads();
    int n = t >> 2, kc = (t & 3) * 16;
    unsigned short o[16];
#pragma unroll
    for (int j = 0; j < 16; ++j) o[j] = tile[kc + j][n];
    unsigned short* dst = &WT[(size_t)(n0 + n) * K + k0 + kc];
    *(uint4*)dst = *(const uint4*)o;
    *(uint4*)(dst + 8) = *(const uint4*)(o + 8);
}

// ================= 256x256 pipelined bf16 GEMM (GEMM1) ======
#define STAGE_A(S, H, KT)                                                              \
    do {                                                                               \
        GLDS16(aS[H][0] + (size_t)(KT) * 64, &Abuf[S][(H) * 8192 + wid * 512]);        \
        GLDS16(aS[H][1] + (size_t)(KT) * 64, &Abuf[S][(H) * 8192 + 4096 + wid * 512]); \
    } while (0)
#define STAGE_B(S, H, KT)                                                              \
    do {                                                                               \
        GLDS16(bS[H][0] + (size_t)(KT) * 64, &Bbuf[S][(H) * 8192 + wid * 512]);        \
        GLDS16(bS[H][1] + (size_t)(KT) * 64, &Bbuf[S][(H) * 8192 + 4096 + wid * 512]); \
    } while (0)

#define LDA_HALF(S, QM)                                                                   \
    do {                                                                                  \
        _Pragma("unroll") for (int mi = 0; mi < 4; ++mi)                                  \
            _Pragma("unroll") for (int kh = 0; kh < 2; ++kh)                              \
                af[mi][kh] =                                                              \
                    *(const bf16x8*)&Abuf[S][((QM) * 8192 + aoff + mi * 1024) ^ (kh * 32)]; \
    } while (0)
#define LDB_HALF(S, QN, BF)                                                               \
    do {                                                                                  \
        _Pragma("unroll") for (int ni = 0; ni < 2; ++ni)                                  \
            _Pragma("unroll") for (int kh = 0; kh < 2; ++kh)                              \
                BF[ni][kh] =                                                              \
                    *(const bf16x8*)&Bbuf[S][((QN) * 8192 + boff + ni * 1024) ^ (kh * 32)]; \
    } while (0)

#define MMAQ(QM, QN, BF)                                                                \
    do {                                                                                \
        _Pragma("unroll") for (int mi = 0; mi < 4; ++mi)                                \
            _Pragma("unroll") for (int ni = 0; ni < 2; ++ni)                            \
                _Pragma("unroll") for (int kh = 0; kh < 2; ++kh)                        \
                    acc[(QM) * 4 + mi][(QN) * 2 + ni] =                                 \
                        MFMA16(af[mi][kh], BF[ni][kh], acc[(QM) * 4 + mi][(QN) * 2 + ni]); \
    } while (0)

#define KTILE_V2(S, T, STG1, STG2, VMOP, RDNEXT)       \
    {                                                  \
        const int s_ = (S);                            \
        LDB_HALF(s_, 1, bf1);                          \
        STG1(STAGE_B(s_ ^ 1, 0, (T) + 1);)             \
        __builtin_amdgcn_s_setprio(1);                 \
        MMAQ(0, 0, bf0);                               \
        __builtin_amdgcn_s_setprio(0);                 \
        WAIT_LGKM0();                                  \
        BARRIER();                                     \
        STG2(STAGE_A(s_, 0, (T) + 2);                  \
             STAGE_B(s_, 1, (T) + 2);)                 \
        __builtin_amdgcn_s_setprio(1);                 \
        MMAQ(0, 1, bf1);                               \
        __builtin_amdgcn_s_setprio(0);                 \
        LDA_HALF(s_, 1);                               \
        __builtin_amdgcn_s_setprio(1);                 \
        MMAQ(1, 1, bf1);                               \
        __builtin_amdgcn_s_setprio(0);                 \
        WAIT_LGKM0();                                  \
        BARRIER();                                     \
        STG2(STAGE_A(s_, 1, (T) + 2);)                 \
        __builtin_amdgcn_s_setprio(1);                 \
        MMAQ(1, 0, bf0);                               \
        __builtin_amdgcn_s_setprio(0);                 \
        VMOP;                                          \
        BARRIER();                                     \
        RDNEXT(LDA_HALF(s_ ^ 1, 0); LDB_HALF(s_ ^ 1, 0, bf0);) \
    }

__global__ __launch_bounds__(512, 2) void gemm256(const unsigned short* __restrict__ A, int lda,
                                                  const unsigned short* __restrict__ BT, int ldb,
                                                  const float* __restrict__ bias0,
                                                  const float* __restrict__ bias1, int nsplit,
                                                  unsigned short* __restrict__ C, int ldc,
                                                  int K, float s0, float s1, int gx) {
    __shared__ __align__(16) unsigned short Abuf[2][16384];
    __shared__ __align__(16) unsigned short Bbuf[2][16384];

    int nwg = gridDim.x, orig = blockIdx.x;
    int cpx = nwg >> 3;
    int wgid = (orig & 7) * cpx + (orig >> 3);
    int tm = wgid / gx, tn = wgid % gx;
    int m0 = tm * 256, n0 = tn * 256;

    int tid = threadIdx.x, lane = tid & 63, wid = tid >> 6;
    int wm = wid >> 2, wn = wid & 3;
    int lrow = lane & 15, lkg = lane >> 4;

    int t5 = tid >> 3;
    int cole = ((tid & 7) ^ ((tid >> 3) & 7)) << 3;
    const unsigned short* aS[2][2];
    const unsigned short* bS[2][2];
#pragma unroll
    for (int H = 0; H < 2; ++H)
#pragma unroll
        for (int c = 0; c < 2; ++c) {
            int rA = (c << 7) | (H << 6) | t5;
            int rB = (((c << 1) | (t5 >> 5)) << 6) | (H << 5) | (t5 & 31);
            aS[H][c] = A + (size_t)(m0 + rA) * lda + cole;
            bS[H][c] = BT + (size_t)(n0 + rB) * ldb + cole;
        }

    int xorc = (lkg * 8) ^ ((lrow & 7) << 3);
    int aoff = wm * 4096 + lrow * 64 + xorc;
    int boff = wn * 2048 + lrow * 64 + xorc;

    f32x4 acc[8][4];
#pragma unroll
    for (int i = 0; i < 8; ++i)
#pragma unroll
        for (int j = 0; j < 4; ++j) acc[i][j] = (f32x4){0.f, 0.f, 0.f, 0.f};
    bf16x8 af[4][2], bf0[2][2], bf1[2][2];

    const int nkt = K >> 6;

    STAGE_A(0, 0, 0); STAGE_A(0, 1, 0); STAGE_B(0, 0, 0); STAGE_B(0, 1, 0);
    STAGE_A(1, 0, 1); STAGE_B(1, 1, 1); STAGE_A(1, 1, 1);
    VM6;
    BARRIER();
    LDA_HALF(0, 0);
    LDB_HALF(0, 0, bf0);

    int t = 0;
    for (; t + 2 < nkt; ++t) KTILE_V2(t & 1, t, KEEP, KEEP, VM6, KEEP);
    KTILE_V2(t & 1, t, KEEP, DROP, VM0, KEEP);
    ++t;
    KTILE_V2(t & 1, t, DROP, DROP, VMNONE, DROP);

#pragma unroll
    for (int ni = 0; ni < 4; ++ni) {
        int col = n0 + wn * 64 + ni * 16 + lrow;
        float bval = (col < nsplit) ? bias0[col] : bias1[col - nsplit];
        float scl = (col < nsplit) ? s0 : s1;
#pragma unroll
        for (int mi = 0; mi < 8; ++mi) {
            int row = m0 + wm * 128 + mi * 16 + lkg * 4;
#pragma unroll
            for (int j = 0; j < 4; ++j)
                C[(size_t)(row + j) * ldc + col] = cvt_bf((acc[mi][ni][j] + bval) * scl);
        }
    }
}

// ================= 128x128 2-blocks/CU bf16 GEMM (GEMM2) =========
#define STG128(S, KT)                                                                  \
    do {                                                                               \
        _Pragma("unroll") for (int i_ = 0; i_ < 4; ++i_)                               \
            GLDS16(Ag + (size_t)(i_ * 32) * lda + (size_t)(KT) * 64,                   \
                   &Abuf[S][i_ * 2048 + wid * 512]);                                   \
        _Pragma("unroll") for (int i_ = 0; i_ < 4; ++i_)                               \
            GLDS16(Bg + (size_t)(i_ * 32) * ldb + (size_t)(KT) * 64,                   \
                   &Bbuf[S][i_ * 2048 + wid * 512]);                                   \
    } while (0)

__global__ __launch_bounds__(256, 2) void gemm128(const unsigned short* __restrict__ A, int lda,
                                                  const unsigned short* __restrict__ BT, int ldb,
                                                  const float* __restrict__ bias0,
                                                  const float* __restrict__ bias1, int nsplit,
                                                  unsigned short* __restrict__ C, int ldc,
                                                  unsigned short* __restrict__ VT,
                                                  int K, int gy) {
    __shared__ __align__(16) unsigned short Abuf[2][8192];  // 2 x 16KB
    __shared__ __align__(16) unsigned short Bbuf[2][8192];

    int b = blockIdx.x;
    int wgid = (b & 7) * (gridDim.x >> 3) + (b >> 3);  // bijective XCD remap
    int tm = wgid % gy, tn = wgid / gy;                // tm-inner within each tn column
    int m0 = tm * 128, n0 = tn * 128;
    int tid = threadIdx.x, lane = tid & 63, wid = tid >> 6;
    int wm = wid >> 1, wn = wid & 1;
    int lrow = lane & 15, lkg = lane >> 4;

    int srow = tid >> 3;
    int cole = ((tid & 7) ^ ((tid >> 3) & 7)) << 3;
    const unsigned short* Ag = A + (size_t)(m0 + srow) * lda + cole;
    const unsigned short* Bg = BT + (size_t)(n0 + srow) * ldb + cole;

    int xorc8 = (lrow & 7) << 3;
    int aoff = (wm * 64 + lrow) * 64;
    int boff = (wn * 64 + lrow) * 64;

    f32x4 acc[4][4];
#pragma unroll
    for (int i2 = 0; i2 < 4; ++i2)
#pragma unroll
        for (int j = 0; j < 4; ++j) acc[i2][j] = (f32x4){0.f, 0.f, 0.f, 0.f};

    const int nkt = K >> 6;
    STG128(0, 0);
    for (int t = 0; t < nkt; ++t) {
        const int cur = t & 1;
        if (t + 1 < nkt) {
            STG128(cur ^ 1, t + 1);
            VM8;
        } else {
            VM0;
        }
        BARRIER();
        bf16x8 af[4][2], bv[4][2];
#pragma unroll
        for (int mi = 0; mi < 4; ++mi)
#pragma unroll
            for (int kh = 0; kh < 2; ++kh)
                af[mi][kh] = *(const bf16x8*)&Abuf[cur][aoff + mi * 1024 + (((kh * 4 + lkg) << 3) ^ xorc8)];
#pragma unroll
        for (int ni = 0; ni < 4; ++ni)
#pragma unroll
            for (int kh = 0; kh < 2; ++kh)
                bv[ni][kh] = *(const bf16x8*)&Bbuf[cur][boff + ni * 1024 + (((kh * 4 + lkg) << 3) ^ xorc8)];
        __builtin_amdgcn_s_setprio(1);
#pragma unroll
        for (int mi = 0; mi < 4; ++mi)
#pragma unroll
            for (int ni = 0; ni < 4; ++ni)
#pragma unroll
                for (int kh = 0; kh < 2; ++kh)
                    acc[mi][ni] = MFMA16(af[mi][kh], bv[ni][kh], acc[mi][ni]);
        __builtin_amdgcn_s_setprio(0);
        BARRIER();
    }

#pragma unroll
    for (int ni = 0; ni < 4; ++ni) {
        int col = n0 + wn * 64 + ni * 16 + lrow;
        float bval = (col < nsplit) ? bias0[col] : bias1[col - nsplit];
#pragma unroll
        for (int mi = 0; mi < 4; ++mi) {
            int row = m0 + wm * 64 + mi * 16 + lkg * 4;
            if (col < nsplit) {
#pragma unroll
                for (int j = 0; j < 4; ++j)
                    C[(size_t)(row + j) * ldc + col] = cvt_bf(acc[mi][ni][j] + bval);
            } else {
                ushort4 o;
                o.x = cvt_bf(acc[mi][ni][0] + bval);
                o.y = cvt_bf(acc[mi][ni][1] + bval);
                o.z = cvt_bf(acc[mi][ni][2] + bval);
                o.w = cvt_bf(acc[mi][ni][3] + bval);
                *(ushort4*)&VT[(size_t)(col - nsplit) * 2048 + row] = o;
            }
        }
    }
}

// ---------------- flash attention: 256 q-rows/block (8 waves x 2 row-groups) ---------
__global__ __launch_bounds__(512) void attn(const unsigned short* __restrict__ q, int ldq,
                                            const unsigned short* __restrict__ k, int ldk,
                                            const unsigned short* __restrict__ vT,
                                            float* __restrict__ out) {
    const int S = 1024, D = 5120, Dh = 40;
    int b = blockIdx.z, h = blockIdx.y, qt = blockIdx.x;
    int t = threadIdx.x, lane = t & 63, wid = t >> 6;
    int lrow = lane & 15, lkg = lane >> 4;

    __shared__ __align__(16) unsigned short Ks[64 * 72];
    __shared__ __align__(16) unsigned short Vs[48 * 72];     // [d][key], rows 40..47 zero
    __shared__ __align__(16) unsigned short Ps[8][16 * 72];

    const size_t qbase = ((size_t)b * S) * ldq + (size_t)h * Dh;
    int q0 = qt * 256 + wid * 32;

    for (int z = t; z < 8 * 72; z += 512) Vs[40 * 72 + z] = 0;

    bf16x8 qf[2][2];
#pragma unroll
    for (int g = 0; g < 2; ++g) {
        const unsigned short* qp = q + qbase + (size_t)(q0 + g * 16 + lrow) * ldq;
        qf[g][0] = *(const bf16x8*)(qp + lkg * 8);
        qf[g][1] = (lkg == 0) ? *(const bf16x8*)(qp + 32) : bf8_zero();
    }

    int rrK = t >> 3, ccK = t & 7;
    int dV = t >> 3, cV = t & 7;
    int dVc = (dV < 40) ? dV : 39;
    const unsigned short* kp = k + ((size_t)b * S) * ldk + (size_t)h * Dh +
                               (size_t)rrK * ldk + ccK * 8;
    const unsigned short* vp = vT + (size_t)(h * Dh + dVc) * 2048 + b * S + cV * 8;
    const size_t kstep = (size_t)64 * ldk;

    uint4 kv0 = make_uint4(0, 0, 0, 0), va0 = make_uint4(0, 0, 0, 0);
    if (ccK < 5) kv0 = *(const uint4*)kp;
    if (dV < 40) va0 = *(const uint4*)vp;
    kp += kstep; vp += 64;

    f32x4 acc[2][3];
#pragma unroll
    for (int g = 0; g < 2; ++g)
#pragma unroll
        for (int nb = 0; nb < 3; ++nb) acc[g][nb] = (f32x4){0.f, 0.f, 0.f, 0.f};
    float mrun[2] = {-INFINITY, -INFINITY}, lrun[2] = {0.f, 0.f};

    for (int kt = 0; kt < 16; ++kt) {
        __syncthreads();
        uint4 w0 = (ccK < 5) ? kv0 : make_uint4(0, 0, 0, 0);
        *(uint4*)&Ks[rrK * 72 + ccK * 8] = w0;
        if (dV < 40) *(uint4*)&Vs[dV * 72 + cV * 8] = va0;
        __syncthreads();
        if (kt + 1 < 16) {
            if (ccK < 5) kv0 = *(const uint4*)kp;
            if (dV < 40) va0 = *(const uint4*)vp;
            kp += kstep; vp += 64;
        }

#pragma unroll
        for (int g = 0; g < 2; ++g) {
            f32x4 sf[4];
            __builtin_amdgcn_s_setprio(1);
#pragma unroll
            for (int nb = 0; nb < 4; ++nb) {
                sf[nb] = (f32x4){0.f, 0.f, 0.f, 0.f};
                bf16x8 kf0 = *(const bf16x8*)&Ks[(nb * 16 + lrow) * 72 + lkg * 8];
                bf16x8 kf1 = *(const bf16x8*)&Ks[(nb * 16 + lrow) * 72 + 32 + lkg * 8];
                sf[nb] = MFMA16(kf0, qf[g][0], sf[nb]);
                sf[nb] = MFMA16(kf1, qf[g][1], sf[nb]);
            }
            __builtin_amdgcn_s_setprio(0);

            float tm = sf[0][0];
#pragma unroll
            for (int nb = 0; nb < 4; ++nb)
#pragma unroll
                for (int i = 0; i < 4; ++i) tm = fmaxf(tm, sf[nb][i]);
            tm = fmaxf(tm, __shfl_xor(tm, 16));
            tm = fmaxf(tm, __shfl_xor(tm, 32));

            float mn = mrun[g], al = 1.0f;
            bool resc = !__all(tm <= mrun[g] + 11.0f);
            if (resc) {
                mn = fmaxf(mrun[g], tm);
                al = EXP2F(mrun[g] - mn);
                mrun[g] = mn;
            }
            float rs = 0.f;
#pragma unroll
            for (int nb = 0; nb < 4; ++nb) {
                bf16x4 pk;
#pragma unroll
                for (int i = 0; i < 4; ++i) {
                    float p = EXP2F(sf[nb][i] - mn);
                    rs += p;
                    pk[i] = (__bf16)p;
                }
                *(bf16x4*)&Ps[wid][lrow * 72 + nb * 16 + lkg * 4] = pk;
            }
            rs += __shfl_xor(rs, 16);
            rs += __shfl_xor(rs, 32);
            lrun[g] = lrun[g] * al + rs;

            if (resc) {
                float alr[4];
#pragma unroll
                for (int i = 0; i < 4; ++i) alr[i] = __shfl(al, lkg * 4 + i);
#pragma unroll
                for (int nb = 0; nb < 3; ++nb)
#pragma unroll
                    for (int i = 0; i < 4; ++i) acc[g][nb][i] *= alr[i];
            }

            __builtin_amdgcn_s_setprio(1);
#pragma unroll
            for (int kk = 0; kk < 2; ++kk) {
                bf16x8 pf = *(const bf16x8*)&Ps[wid][lrow * 72 + kk * 32 + lkg * 8];
#pragma unroll
                for (int nb = 0; nb < 3; ++nb) {
                    bf16x8 vf = *(const bf16x8*)&Vs[(nb * 16 + lrow) * 72 + kk * 32 + lkg * 8];
                    acc[g][nb] = MFMA16(pf, vf, acc[g][nb]);
                }
            }
            __builtin_amdgcn_s_setprio(0);
        }
    }

#pragma unroll
    for (int g = 0; g < 2; ++g) {
        float lr[4];
#pragma unroll
        for (int i = 0; i < 4; ++i) lr[i] = __shfl(lrun[g], lkg * 4 + i);
#pragma unroll
        for (int i = 0; i < 4; ++i) {
            float inv = 1.0f / lr[i];
            int s = q0 + g * 16 + lkg * 4 + i;
#pragma unroll
            for (int nb = 0; nb < 3; ++nb) {
                int d = nb * 16 + lrow;
                if (d < Dh) out[((size_t)(b * S + s)) * D + h * Dh + d] = acc[g][nb][i] * inv;
            }
        }
    }
}

extern "C" void kernel_launch(void* const* d_in, const int* in_sizes, int n_in,
                              void* d_out, int out_size, void* d_ws, size_t ws_size,
                              hipStream_t stream) {
    const int M = 2048, D = 5120, L = 1536, NQ = D + L /*6656*/, NKV = 2 * D /*10240*/;
    const float* x  = (const float*)d_in[0];
    const float* Wq = (const float*)d_in[1];
    const float* bq = (const float*)d_in[2];
    const float* Wc = (const float*)d_in[3];
    const float* bc = (const float*)d_in[4];
    const float* Wk = (const float*)d_in[5];
    const float* bk = (const float*)d_in[6];
    const float* Wv = (const float*)d_in[7];
    const float* bv = (const float*)d_in[8];
    float* out = (float*)d_out;

    unsigned short* ws = (unsigned short*)d_ws;
    size_t off = 0;
    unsigned short* xb    = ws + off; off += (size_t)M * D;
    unsigned short* WqcT  = ws + off; off += (size_t)NQ * D;   // [Wq|Wc]^T
    unsigned short* WkvT  = ws + off; off += (size_t)NKV * L;  // [Wk|Wv]^T
    unsigned short* qkvb  = ws + off; off += (size_t)M * NQ;   // [q | kv_latent]
    unsigned short* kvout = ws + off; off += (size_t)M * NKV;  // [k | (v unused)]
    unsigned short* vTb   = ws + off; off += (size_t)D * M;    // v^T [5120][2048]

    prep<<<17280, 256, 0, stream>>>(x, Wq, Wc, Wk, Wv, xb, WqcT, WkvT);

    const float qscale = 1.4426950408889634f / 6.324555320336759f;  // log2(e)/sqrt(40)

    // GEMM1: [q | kv_latent] = x @ [Wq | Wc]   grid 208 (8x26), 256^2 pipelined
    gemm256<<<dim3((NQ / 256) * (M / 256)), 512, 0, stream>>>(xb, D, WqcT, D, bq, bc, D,
                                                              qkvb, NQ, D, qscale, 1.0f,
                                                              NQ / 256);
    // GEMM2: [k | v] = kv_latent @ [Wk | Wv]; k -> kvout, v -> vTb (transposed epilogue)
    gemm128<<<dim3((NKV / 128) * (M / 128)), 256, 0, stream>>>(qkvb + D, NQ, WkvT, L, bk, bv, D,
                                                               kvout, NKV, vTb, L, M / 128);

    attn<<<dim3(1024 / 256, 128, 2), 512, 0, stream>>>(qkvb, NQ, kvout, NKV, vTb, out);
}